// Round 16
// baseline (1106.003 us; speedup 1.0000x reference)
//
#include <hip/hip_runtime.h>
#include <math.h>

#define NTOK 131072
#define HDIM 256
#define DDIM 512
#define FDIM 1024
#define EDIM 16
#define TBLK 64
#define FCH  128
#define KST  32
#define XST  40    // f16 row stride (80 B, 16B-aligned): 2-way-free frag reads
#define HST  132   // f32 row stride (528 B, 16B-aligned): 2-way-free GEMM2 reads

typedef __attribute__((ext_vector_type(8))) _Float16 v8h;
typedef __attribute__((ext_vector_type(4))) _Float16 v4h;
typedef __attribute__((ext_vector_type(4))) float v4f;

// f32 -> fp16 hi + lo residual (R14/R15-validated numerics)
__device__ __forceinline__ void f2h2(float v, _Float16& h, _Float16& l) {
    h = (_Float16)v;
    l = (_Float16)(v - (float)h);
}

// LDS 33792 B (4 blocks/CU):
//  staging: xs_h[64][40] @0 (5120), xs_l @5120,
//           ws_h[128][40] @10240 (10240), ws_l @20480   (total 30720)
//  GEMM2:   hs f32 [64][132] = 33792 aliases @0 (barrier-separated)
// FCH=128 at acc[2][4]=32 VGPR via TBLK=64 (wave tile 32x64) — avoids R14's
// 64-reg-acc spill. (256,2) remains the only proven no-spill launch config.
__global__ __launch_bounds__(256, 2)
void router_mfma8(const float* __restrict__ inp,
                  const float* __restrict__ cnd,
                  const float* __restrict__ W1,
                  const float* __restrict__ b1,
                  const float* __restrict__ W2,
                  const float* __restrict__ b2,
                  float* __restrict__ out)
{
    __shared__ __align__(16) char smem[33792];
    _Float16* xs_h = (_Float16*)(smem);
    _Float16* xs_l = (_Float16*)(smem + 5120);
    _Float16* ws_h = (_Float16*)(smem + 10240);
    _Float16* ws_l = (_Float16*)(smem + 20480);
    float*    hs   = (float*)(smem);          // alias, barrier-separated

    const int tid  = threadIdx.x;
    const int lane = tid & 63;
    const int w    = tid >> 6;        // wave 0..3
    const int wr   = w >> 1;          // token half (32)
    const int wf   = w & 1;           // F half (64 of the 128-chunk)
    const int l15  = lane & 15;
    const int l4   = lane >> 4;
    const int t0   = blockIdx.x * TBLK;
    const int ty   = tid >> 4;        // 0..15: token group (4) for GEMM2/epilogue
    const int tx   = tid & 15;        // expert lane
    const int kq   = tid & 7;         // x staging: k-quad
    const int xr   = tid >> 3;        // x staging: base row (0..31)
    const int fcl  = tid & 127;       // W1 staging: F col
    const int kg   = tid >> 7;        // W1 staging: 0..1

    float lg[4];
    {
        const float bb = b2[tx];
#pragma unroll
        for (int i = 0; i < 4; ++i) lg[i] = bb;
    }

    for (int fc = 0; fc < FDIM; fc += FCH) {
        v4f acc[2][4];   // 32 VGPR — single accumulator, all 3 split terms
#pragma unroll
        for (int mf = 0; mf < 2; ++mf)
#pragma unroll
            for (int nf = 0; nf < 4; ++nf)
                acc[mf][nf] = (v4f){0.f,0.f,0.f,0.f};

        for (int st = 0; st < 16; ++st) {
            const int kc = st * KST;
            __syncthreads();   // prior MFMA reads / prior GEMM2 hs reads done
            // ---- stage x tile [64 tok][32 k] as f16 hi/lo ----
            {
                const float* src = (kc < HDIM)
                    ? (inp + (size_t)t0 * HDIM + kc)
                    : (cnd + (size_t)t0 * HDIM + (kc - HDIM));
#pragma unroll
                for (int p = 0; p < 2; ++p) {
                    const int row = xr + 32 * p;
                    const float4 v = *(const float4*)(src + (size_t)row * HDIM + kq * 4);
                    _Float16 h0,l0,h1,l1,h2,l2,h3,l3;
                    f2h2(v.x,h0,l0); f2h2(v.y,h1,l1); f2h2(v.z,h2,l2); f2h2(v.w,h3,l3);
                    v4h hh, hl;
                    hh[0]=h0; hh[1]=h1; hh[2]=h2; hh[3]=h3;
                    hl[0]=l0; hl[1]=l1; hl[2]=l2; hl[3]=l3;
                    *(v4h*)(xs_h + row * XST + kq * 4) = hh;
                    *(v4h*)(xs_l + row * XST + kq * 4) = hl;
                }
            }
            // ---- stage W1 tile [32 k][128 F] -> ws[F][k] ----
#pragma unroll
            for (int s = 0; s < 4; ++s) {
                const int kb = 8 * s + 4 * kg;     // covers {0,4,...,28}
                const float u0 = W1[(size_t)(kc + kb + 0) * FDIM + fc + fcl];
                const float u1 = W1[(size_t)(kc + kb + 1) * FDIM + fc + fcl];
                const float u2 = W1[(size_t)(kc + kb + 2) * FDIM + fc + fcl];
                const float u3 = W1[(size_t)(kc + kb + 3) * FDIM + fc + fcl];
                _Float16 h0,l0,h1,l1,h2,l2,h3,l3;
                f2h2(u0,h0,l0); f2h2(u1,h1,l1); f2h2(u2,h2,l2); f2h2(u3,h3,l3);
                v4h hh, hl;
                hh[0]=h0; hh[1]=h1; hh[2]=h2; hh[3]=h3;
                hl[0]=l0; hl[1]=l1; hl[2]=l2; hl[3]=l3;
                *(v4h*)(ws_h + fcl * XST + kb) = hh;
                *(v4h*)(ws_l + fcl * XST + kb) = hl;
            }
            __syncthreads();
            // ---- MFMA 16x16x32 f16: A resident (16 reg), B streamed ----
            {
                v8h ah[2], al[2];
#pragma unroll
                for (int mf = 0; mf < 2; ++mf) {
                    const int off = (32 * wr + 16 * mf + l15) * XST + 8 * l4;
                    ah[mf] = *(const v8h*)(xs_h + off);
                    al[mf] = *(const v8h*)(xs_l + off);
                }
#pragma unroll
                for (int nf = 0; nf < 4; ++nf) {
                    const int off = (64 * wf + 16 * nf + l15) * XST + 8 * l4;
                    const v8h bh = *(const v8h*)(ws_h + off);
                    const v8h bl = *(const v8h*)(ws_l + off);
#pragma unroll
                    for (int mf = 0; mf < 2; ++mf) {
                        acc[mf][nf] = __builtin_amdgcn_mfma_f32_16x16x32_f16(ah[mf], bh, acc[mf][nf], 0, 0, 0);
                        acc[mf][nf] = __builtin_amdgcn_mfma_f32_16x16x32_f16(al[mf], bh, acc[mf][nf], 0, 0, 0);
                        acc[mf][nf] = __builtin_amdgcn_mfma_f32_16x16x32_f16(ah[mf], bl, acc[mf][nf], 0, 0, 0);
                    }
                }
            }
        }
        __syncthreads();   // all MFMA xs/ws reads done; hs may alias them

        // ---- bias + exact GELU -> hs (f32, [64][132]) ----
        {
            float b1v[4];
#pragma unroll
            for (int nf = 0; nf < 4; ++nf)
                b1v[nf] = b1[fc + 64 * wf + 16 * nf + l15];
#pragma unroll
            for (int mf = 0; mf < 2; ++mf)
#pragma unroll
                for (int nf = 0; nf < 4; ++nf)
#pragma unroll
                    for (int r = 0; r < 4; ++r) {
                        const float v = acc[mf][nf][r] + b1v[nf];
                        const int tok  = 32 * wr + 16 * mf + 4 * l4 + r;
                        const int fcol = 64 * wf + 16 * nf + l15;
                        hs[tok * HST + fcol]
                            = 0.5f * v * (1.0f + erff(v * 0.70710678118654752f));
                    }
        }
        __syncthreads();

        // ---- GEMM2: direct per-expert dot over 128 cols (broadcast reads) ----
#pragma unroll
        for (int jb = 0; jb < 32; ++jb) {
            float w2v[4];
#pragma unroll
            for (int j = 0; j < 4; ++j)
                w2v[j] = W2[(size_t)(fc + jb * 4 + j) * EDIM + tx];
#pragma unroll
            for (int i = 0; i < 4; ++i) {
                const float4 hv = *(const float4*)(hs + (ty * 4 + i) * HST + jb * 4);
                lg[i] = fmaf(hv.x, w2v[0], lg[i]);
                lg[i] = fmaf(hv.y, w2v[1], lg[i]);
                lg[i] = fmaf(hv.z, w2v[2], lg[i]);
                lg[i] = fmaf(hv.w, w2v[3], lg[i]);
            }
        }
        // next fc pass's first staging barrier protects hs
    }

    // ---- softmax + clip + top-2 + writes (R4-proven 16-lane butterflies) ----
#pragma unroll
    for (int i = 0; i < 4; ++i) {
        const int t = t0 + ty * 4 + i;
        float mx = lg[i];
#pragma unroll
        for (int m = 1; m < 16; m <<= 1) mx = fmaxf(mx, __shfl_xor(mx, m, 64));
        float p = expf(lg[i] - mx);
        float s = p;
#pragma unroll
        for (int m = 1; m < 16; m <<= 1) s += __shfl_xor(s, m, 64);
        float pr = p / s;
        pr = fminf(fmaxf(pr, 1e-9f), 1.0f - 1e-9f);

        float v1 = pr; int i1 = tx;
#pragma unroll
        for (int m = 1; m < 16; m <<= 1) {
            const float vo = __shfl_xor(v1, m, 64);
            const int   io = __shfl_xor(i1, m, 64);
            if (vo > v1 || (vo == v1 && io < i1)) { v1 = vo; i1 = io; }
        }
        float v2 = (tx == i1) ? -1.0f : pr; int i2 = tx;
#pragma unroll
        for (int m = 1; m < 16; m <<= 1) {
            const float vo = __shfl_xor(v2, m, 64);
            const int   io = __shfl_xor(i2, m, 64);
            if (vo > v2 || (vo == v2 && io < i2)) { v2 = vo; i2 = io; }
        }
        const float rs = 1.0f / (v1 + v2);

        float* om  = out + (size_t)t * EDIM;
        float* orp = out + (size_t)NTOK * 18 + (size_t)t * EDIM;
        float* opf = out + (size_t)NTOK * 34 + (size_t)t * EDIM;
        om[tx]  = (tx == i1 || tx == i2) ? 1.0f : 0.0f;
        orp[tx] = (tx == i1) ? v1 * rs : ((tx == i2) ? v2 * rs : 0.0f);
        opf[tx] = pr;
        if (tx == 0) {
            float2* oi = (float2*)(out + (size_t)NTOK * 16 + (size_t)t * 2);
            *oi = make_float2((float)i1, (float)i2);
        }
    }
}

extern "C" void kernel_launch(void* const* d_in, const int* in_sizes, int n_in,
                              void* d_out, int out_size, void* d_ws, size_t ws_size,
                              hipStream_t stream)
{
    const float* inp = (const float*)d_in[0];
    const float* cnd = (const float*)d_in[1];
    const float* W1  = (const float*)d_in[2];
    const float* b1  = (const float*)d_in[3];
    const float* W2  = (const float*)d_in[4];
    const float* b2  = (const float*)d_in[5];
    float* out = (float*)d_out;

    dim3 grid(NTOK / TBLK), block(256);
    hipLaunchKernelGGL(router_mfma8, grid, block, 0, stream,
                       inp, cnd, W1, b1, W2, b2, out);
}